// Round 1
// baseline (973.648 us; speedup 1.0000x reference)
//
#include <hip/hip_runtime.h>
#include <math.h>

// ---------------- degree / normalization ----------------

__global__ void k_init_deg(float* __restrict__ deg, int n) {
    int i = blockIdx.x * blockDim.x + threadIdx.x;
    if (i < n) deg[i] = 1.0f;   // self-loop
}

__global__ void k_count_deg(const int* __restrict__ dst, float* __restrict__ deg, int e) {
    int i = blockIdx.x * blockDim.x + threadIdx.x;
    if (i < e) atomicAdd(&deg[dst[i]], 1.0f);
}

__global__ void k_deg_to_dis(float* __restrict__ deg, int n) {
    int i = blockIdx.x * blockDim.x + threadIdx.x;
    if (i < n) deg[i] = rsqrtf(deg[i]);   // deg >= 1 always
}

// ---------------- layer 1 linear: h[n,16] = x[n,128] @ W[128,16] ----------------

__global__ void k_linear1(const float* __restrict__ x, const float* __restrict__ W,
                          float* __restrict__ h, int n) {
    __shared__ float sW[128 * 16];
    for (int i = threadIdx.x; i < 128 * 16; i += blockDim.x) sW[i] = W[i];
    __syncthreads();
    int t = blockIdx.x * blockDim.x + threadIdx.x;
    int node = t >> 4, c = t & 15;
    if (node >= n) return;
    const float* xr = x + (size_t)node * 128;
    float acc = 0.f;
#pragma unroll 8
    for (int k = 0; k < 128; k++) acc += xr[k] * sW[k * 16 + c];
    h[(size_t)node * 16 + c] = acc;
}

// ---------------- aggregation (16 channels) ----------------

// self-loop term: out[n,c] = h[n,c] * dis[n]^2  (dis^2 = 1/deg)
__global__ void k_init_agg16(const float* __restrict__ h, const float* __restrict__ dis,
                             float* __restrict__ out, int n) {
    int t = blockIdx.x * blockDim.x + threadIdx.x;
    if (t >= n * 16) return;
    int node = t >> 4;
    float d = dis[node];
    out[t] = h[t] * d * d;
}

__global__ void k_edge_agg16(const float* __restrict__ h, const int* __restrict__ src,
                             const int* __restrict__ dst, const float* __restrict__ dis,
                             float* __restrict__ out, int e) {
    long long t = (long long)blockIdx.x * blockDim.x + threadIdx.x;
    long long ed = t >> 4;
    int c = (int)(t & 15);
    if (ed >= e) return;
    int s = src[ed], d = dst[ed];
    float nrm = dis[s] * dis[d];
    atomicAdd(&out[(size_t)d * 16 + c], h[(size_t)s * 16 + c] * nrm);
}

// ---------------- bias + relu + 16x16 linear ----------------

__global__ void k_brl16(const float* __restrict__ in, const float* __restrict__ b,
                        const float* __restrict__ W, float* __restrict__ out, int n) {
    __shared__ float sW[256];
    __shared__ float sb[16];
    if (threadIdx.x < 256) sW[threadIdx.x] = W[threadIdx.x];
    if (threadIdx.x < 16) sb[threadIdx.x] = b[threadIdx.x];
    __syncthreads();
    int t = blockIdx.x * blockDim.x + threadIdx.x;
    int node = t >> 4, c = t & 15;
    if (node >= n) return;
    const float* ir = in + (size_t)node * 16;
    float acc = 0.f;
#pragma unroll
    for (int k = 0; k < 16; k++) {
        float v = ir[k] + sb[k];
        v = v > 0.f ? v : 0.f;
        acc += v * sW[k * 16 + c];
    }
    out[(size_t)node * 16 + c] = acc;
}

// ---------------- bias + relu + 16x2 linear ----------------

__global__ void k_brl2(const float* __restrict__ in, const float* __restrict__ b,
                       const float* __restrict__ W, float* __restrict__ out, int n) {
    int node = blockIdx.x * blockDim.x + threadIdx.x;
    if (node >= n) return;
    const float* ir = in + (size_t)node * 16;
    float a0 = 0.f, a1 = 0.f;
#pragma unroll
    for (int k = 0; k < 16; k++) {
        float v = ir[k] + b[k];
        v = v > 0.f ? v : 0.f;
        a0 += v * W[k * 2 + 0];
        a1 += v * W[k * 2 + 1];
    }
    out[(size_t)node * 2 + 0] = a0;
    out[(size_t)node * 2 + 1] = a1;
}

// ---------------- aggregation (2 channels) ----------------

__global__ void k_init_agg2(const float* __restrict__ h, const float* __restrict__ dis,
                            float* __restrict__ out, int n) {
    int t = blockIdx.x * blockDim.x + threadIdx.x;
    if (t >= n * 2) return;
    int node = t >> 1;
    float d = dis[node];
    out[t] = h[t] * d * d;
}

__global__ void k_edge_agg2(const float* __restrict__ h, const int* __restrict__ src,
                            const int* __restrict__ dst, const float* __restrict__ dis,
                            float* __restrict__ out, int e) {
    int ed = blockIdx.x * blockDim.x + threadIdx.x;
    if (ed >= e) return;
    int s = src[ed], d = dst[ed];
    float nrm = dis[s] * dis[d];
    atomicAdd(&out[(size_t)d * 2 + 0], h[(size_t)s * 2 + 0] * nrm);
    atomicAdd(&out[(size_t)d * 2 + 1], h[(size_t)s * 2 + 1] * nrm);
}

// ---------------- bias + log_softmax (C=2) ----------------

__global__ void k_lsm(const float* __restrict__ in, const float* __restrict__ b,
                      float* __restrict__ out, int n) {
    int node = blockIdx.x * blockDim.x + threadIdx.x;
    if (node >= n) return;
    float z0 = in[(size_t)node * 2 + 0] + b[0];
    float z1 = in[(size_t)node * 2 + 1] + b[1];
    float m = fmaxf(z0, z1);
    float l = m + logf(expf(z0 - m) + expf(z1 - m));
    out[(size_t)node * 2 + 0] = z0 - l;
    out[(size_t)node * 2 + 1] = z1 - l;
}

// ---------------- launch ----------------

extern "C" void kernel_launch(void* const* d_in, const int* in_sizes, int n_in,
                              void* d_out, int out_size, void* d_ws, size_t ws_size,
                              hipStream_t stream) {
    const float* x  = (const float*)d_in[0];
    const int*   ei = (const int*)d_in[1];
    const float* W1 = (const float*)d_in[2];
    const float* b1 = (const float*)d_in[3];
    const float* W2 = (const float*)d_in[4];
    const float* b2 = (const float*)d_in[5];
    const float* W3 = (const float*)d_in[6];
    const float* b3 = (const float*)d_in[7];
    float* out = (float*)d_out;

    const int N = in_sizes[0] / 128;
    const int E = in_sizes[1] / 2;
    const int* src = ei;
    const int* dst = ei + E;

    // workspace layout (256B aligned chunks)
    char* ws = (char*)d_ws;
    size_t off = 0;
    auto alloc = [&](size_t bytes) {
        void* p = ws + off;
        off += (bytes + 255) & ~(size_t)255;
        return p;
    };
    float* dis  = (float*)alloc((size_t)N * sizeof(float));
    float* bufA = (float*)alloc((size_t)N * 16 * sizeof(float));
    float* bufB = (float*)alloc((size_t)N * 16 * sizeof(float));
    float* bufC = (float*)alloc((size_t)N * 2 * sizeof(float));
    float* bufD = (float*)alloc((size_t)N * 2 * sizeof(float));

    const int B = 256;
    auto g = [&](long long work) { return (int)((work + B - 1) / B); };

    // degree -> dis
    k_init_deg<<<g(N), B, 0, stream>>>(dis, N);
    k_count_deg<<<g(E), B, 0, stream>>>(dst, dis, E);
    k_deg_to_dis<<<g(N), B, 0, stream>>>(dis, N);

    // layer 1
    k_linear1<<<g((long long)N * 16), B, 0, stream>>>(x, W1, bufA, N);
    k_init_agg16<<<g((long long)N * 16), B, 0, stream>>>(bufA, dis, bufB, N);
    k_edge_agg16<<<g((long long)E * 16), B, 0, stream>>>(bufA, src, dst, dis, bufB, E);

    // layer 2 (bias1+relu fused into linear2)
    k_brl16<<<g((long long)N * 16), B, 0, stream>>>(bufB, b1, W2, bufA, N);
    k_init_agg16<<<g((long long)N * 16), B, 0, stream>>>(bufA, dis, bufB, N);
    k_edge_agg16<<<g((long long)E * 16), B, 0, stream>>>(bufA, src, dst, dis, bufB, E);

    // layer 3 (bias2+relu fused into linear3)
    k_brl2<<<g(N), B, 0, stream>>>(bufB, b2, W3, bufC, N);
    k_init_agg2<<<g((long long)N * 2), B, 0, stream>>>(bufC, dis, bufD, N);
    k_edge_agg2<<<g(E), B, 0, stream>>>(bufC, src, dst, dis, bufD, E);

    // bias3 + log_softmax
    k_lsm<<<g(N), B, 0, stream>>>(bufD, b3, out, N);
}

// Round 2
// 779.752 us; speedup vs baseline: 1.2487x; 1.2487x over previous
//
#include <hip/hip_runtime.h>
#include <math.h>

// ================= CSR build =================

__global__ void k_zero(int* __restrict__ c, int n) {
    int i = blockIdx.x * blockDim.x + threadIdx.x;
    if (i < n) c[i] = 0;
}

__global__ void k_count(const int* __restrict__ dst, int* __restrict__ c, int e) {
    int i = blockIdx.x * blockDim.x + threadIdx.x;
    if (i < e) atomicAdd(&c[dst[i]], 1);
}

__global__ void k_dis(const int* __restrict__ c, float* __restrict__ dis, int n) {
    int i = blockIdx.x * blockDim.x + threadIdx.x;
    if (i < n) dis[i] = rsqrtf((float)(c[i] + 1));   // +1 self-loop, always >= 1
}

// scan step 1: per-block (2048 elems) exclusive scan of counts -> rs, block totals -> bsum
__global__ void k_scan1(const int* __restrict__ counts, int* __restrict__ rs,
                        int* __restrict__ bsum, int n) {
    __shared__ int sd[256];
    int base = blockIdx.x * 2048 + threadIdx.x * 8;
    int v[8];
    int ts = 0;
#pragma unroll
    for (int j = 0; j < 8; j++) {
        int idx = base + j;
        v[j] = ts;                              // exclusive prefix within thread
        ts += (idx < n) ? counts[idx] : 0;
    }
    sd[threadIdx.x] = ts;
    __syncthreads();
    for (int ofs = 1; ofs < 256; ofs <<= 1) {
        int t = (threadIdx.x >= (unsigned)ofs) ? sd[threadIdx.x - ofs] : 0;
        __syncthreads();
        sd[threadIdx.x] += t;
        __syncthreads();
    }
    int excl = (threadIdx.x == 0) ? 0 : sd[threadIdx.x - 1];
#pragma unroll
    for (int j = 0; j < 8; j++) {
        int idx = base + j;
        if (idx < n) rs[idx] = excl + v[j];
    }
    if (threadIdx.x == 255) bsum[blockIdx.x] = sd[255];
}

// scan step 2: single block, exclusive scan of block sums (nb <= 256)
__global__ void k_scan2(int* __restrict__ bsum, int nb) {
    __shared__ int sd[256];
    int orig = (threadIdx.x < (unsigned)nb) ? bsum[threadIdx.x] : 0;
    sd[threadIdx.x] = orig;
    __syncthreads();
    for (int ofs = 1; ofs < 256; ofs <<= 1) {
        int t = (threadIdx.x >= (unsigned)ofs) ? sd[threadIdx.x - ofs] : 0;
        __syncthreads();
        sd[threadIdx.x] += t;
        __syncthreads();
    }
    if (threadIdx.x < (unsigned)nb) bsum[threadIdx.x] = sd[threadIdx.x] - orig;
}

// scan step 3: add block offsets, copy to cursor, cap row_start[n]=e
__global__ void k_scan3(int* __restrict__ rs, int* __restrict__ cursor,
                        const int* __restrict__ bsum, int n, int e) {
    int i = blockIdx.x * blockDim.x + threadIdx.x;
    if (i < n) {
        int v = rs[i] + bsum[i >> 11];
        rs[i] = v;
        cursor[i] = v;
    }
    if (i == 0) rs[n] = e;
}

__global__ void k_scatter(const int* __restrict__ src, const int* __restrict__ dst,
                          int* __restrict__ cursor, int* __restrict__ col, int e) {
    int i = blockIdx.x * blockDim.x + threadIdx.x;
    if (i < e) {
        int d = dst[i];
        int pos = atomicAdd(&cursor[d], 1);
        col[pos] = src[i];
    }
}

// ================= linears (output pre-scaled by dis[node]) =================

// hs[n,16] = (x[n,128] @ W[128,16]) * dis[n]
__global__ void k_linear1s(const float* __restrict__ x, const float* __restrict__ W,
                           const float* __restrict__ dis, float* __restrict__ hs, int n) {
    __shared__ float sW[128 * 16];
    for (int i = threadIdx.x; i < 128 * 16; i += blockDim.x) sW[i] = W[i];
    __syncthreads();
    int t = blockIdx.x * blockDim.x + threadIdx.x;
    int node = t >> 4, c = t & 15;
    if (node >= n) return;
    const float* xr = x + (size_t)node * 128;
    float acc = 0.f;
#pragma unroll 8
    for (int k = 0; k < 128; k++) acc += xr[k] * sW[k * 16 + c];
    hs[(size_t)node * 16 + c] = acc * dis[node];
}

// hs[n,16] = (relu(in[n,16]+b) @ W[16,16]) * dis[n]
__global__ void k_brl16s(const float* __restrict__ in, const float* __restrict__ b,
                         const float* __restrict__ W, const float* __restrict__ dis,
                         float* __restrict__ hs, int n) {
    __shared__ float sW[256];
    __shared__ float sb[16];
    if (threadIdx.x < 256) sW[threadIdx.x] = W[threadIdx.x];
    if (threadIdx.x < 16) sb[threadIdx.x] = b[threadIdx.x];
    __syncthreads();
    int t = blockIdx.x * blockDim.x + threadIdx.x;
    int node = t >> 4, c = t & 15;
    if (node >= n) return;
    const float* ir = in + (size_t)node * 16;
    float acc = 0.f;
#pragma unroll
    for (int k = 0; k < 16; k++) {
        float v = ir[k] + sb[k];
        v = v > 0.f ? v : 0.f;
        acc += v * sW[k * 16 + c];
    }
    hs[(size_t)node * 16 + c] = acc * dis[node];
}

// hs2[n,2] = (relu(in[n,16]+b) @ W[16,2]) * dis[n]
__global__ void k_brl2s(const float* __restrict__ in, const float* __restrict__ b,
                        const float* __restrict__ W, const float* __restrict__ dis,
                        float* __restrict__ hs2, int n) {
    int node = blockIdx.x * blockDim.x + threadIdx.x;
    if (node >= n) return;
    const float* ir = in + (size_t)node * 16;
    float a0 = 0.f, a1 = 0.f;
#pragma unroll
    for (int k = 0; k < 16; k++) {
        float v = ir[k] + b[k];
        v = v > 0.f ? v : 0.f;
        a0 += v * W[k * 2 + 0];
        a1 += v * W[k * 2 + 1];
    }
    float d = dis[node];
    hs2[(size_t)node * 2 + 0] = a0 * d;
    hs2[(size_t)node * 2 + 1] = a1 * d;
}

// ================= pull aggregation (no atomics) =================
// out[n,c] = (hs[n,c] + sum_{s in in(n)} hs[s,c]) * dis[n]

__global__ void k_pull16(const float* __restrict__ hs, const int* __restrict__ rs,
                         const int* __restrict__ col, const float* __restrict__ dis,
                         float* __restrict__ out, int n) {
    int t = blockIdx.x * blockDim.x + threadIdx.x;
    int node = t >> 4, c = t & 15;
    if (node >= n) return;
    int b = rs[node], e2 = rs[node + 1];
    float acc = hs[(size_t)node * 16 + c];
    for (int i = b; i < e2; i++) {
        int s = col[i];
        acc += hs[(size_t)s * 16 + c];
    }
    out[(size_t)node * 16 + c] = acc * dis[node];
}

__global__ void k_pull2(const float* __restrict__ hs2, const int* __restrict__ rs,
                        const int* __restrict__ col, const float* __restrict__ dis,
                        float* __restrict__ out, int n) {
    int node = blockIdx.x * blockDim.x + threadIdx.x;
    if (node >= n) return;
    int b = rs[node], e2 = rs[node + 1];
    float a0 = hs2[(size_t)node * 2 + 0];
    float a1 = hs2[(size_t)node * 2 + 1];
    for (int i = b; i < e2; i++) {
        int s = col[i];
        a0 += hs2[(size_t)s * 2 + 0];
        a1 += hs2[(size_t)s * 2 + 1];
    }
    float d = dis[node];
    out[(size_t)node * 2 + 0] = a0 * d;
    out[(size_t)node * 2 + 1] = a1 * d;
}

// ================= bias + log_softmax (C=2) =================

__global__ void k_lsm(const float* __restrict__ in, const float* __restrict__ b,
                      float* __restrict__ out, int n) {
    int node = blockIdx.x * blockDim.x + threadIdx.x;
    if (node >= n) return;
    float z0 = in[(size_t)node * 2 + 0] + b[0];
    float z1 = in[(size_t)node * 2 + 1] + b[1];
    float m = fmaxf(z0, z1);
    float l = m + logf(expf(z0 - m) + expf(z1 - m));
    out[(size_t)node * 2 + 0] = z0 - l;
    out[(size_t)node * 2 + 1] = z1 - l;
}

// ================= launch =================

extern "C" void kernel_launch(void* const* d_in, const int* in_sizes, int n_in,
                              void* d_out, int out_size, void* d_ws, size_t ws_size,
                              hipStream_t stream) {
    const float* x  = (const float*)d_in[0];
    const int*   ei = (const int*)d_in[1];
    const float* W1 = (const float*)d_in[2];
    const float* b1 = (const float*)d_in[3];
    const float* W2 = (const float*)d_in[4];
    const float* b2 = (const float*)d_in[5];
    const float* W3 = (const float*)d_in[6];
    const float* b3 = (const float*)d_in[7];
    float* out = (float*)d_out;

    const int N = in_sizes[0] / 128;
    const int E = in_sizes[1] / 2;
    const int* src = ei;
    const int* dst = ei + E;

    char* ws = (char*)d_ws;
    size_t off = 0;
    auto alloc = [&](size_t bytes) {
        void* p = ws + off;
        off += (bytes + 255) & ~(size_t)255;
        return p;
    };
    int*   counts = (int*)alloc((size_t)N * sizeof(int));
    int*   rowst  = (int*)alloc((size_t)(N + 1) * sizeof(int));
    int*   cursor = (int*)alloc((size_t)N * sizeof(int));
    int*   bsum   = (int*)alloc(256 * sizeof(int));
    int*   col    = (int*)alloc((size_t)E * sizeof(int));
    float* dis    = (float*)alloc((size_t)N * sizeof(float));
    float* bufA   = (float*)alloc((size_t)N * 16 * sizeof(float));
    float* bufB   = (float*)alloc((size_t)N * 16 * sizeof(float));
    float* bufC   = (float*)alloc((size_t)N * 2 * sizeof(float));
    float* bufD   = (float*)alloc((size_t)N * 2 * sizeof(float));

    const int B = 256;
    auto g = [&](long long work) { return (int)((work + B - 1) / B); };
    const int NB = (N + 2047) / 2048;   // scan blocks (<=256 for N<=524288)

    // ---- CSR build ----
    k_zero<<<g(N), B, 0, stream>>>(counts, N);
    k_count<<<g(E), B, 0, stream>>>(dst, counts, E);
    k_dis<<<g(N), B, 0, stream>>>(counts, dis, N);
    k_scan1<<<NB, 256, 0, stream>>>(counts, rowst, bsum, N);
    k_scan2<<<1, 256, 0, stream>>>(bsum, NB);
    k_scan3<<<g(N), B, 0, stream>>>(rowst, cursor, bsum, N, E);
    k_scatter<<<g(E), B, 0, stream>>>(src, dst, cursor, col, E);

    // ---- layer 1 ----
    k_linear1s<<<g((long long)N * 16), B, 0, stream>>>(x, W1, dis, bufA, N);
    k_pull16<<<g((long long)N * 16), B, 0, stream>>>(bufA, rowst, col, dis, bufB, N);

    // ---- layer 2 ----
    k_brl16s<<<g((long long)N * 16), B, 0, stream>>>(bufB, b1, W2, dis, bufA, N);
    k_pull16<<<g((long long)N * 16), B, 0, stream>>>(bufA, rowst, col, dis, bufB, N);

    // ---- layer 3 ----
    k_brl2s<<<g(N), B, 0, stream>>>(bufB, b2, W3, dis, bufC, N);
    k_pull2<<<g(N), B, 0, stream>>>(bufC, rowst, col, dis, bufD, N);

    // ---- log_softmax ----
    k_lsm<<<g(N), B, 0, stream>>>(bufD, b3, out, N);
}